// Round 7
// baseline (465.767 us; speedup 1.0000x reference)
//
#include <hip/hip_runtime.h>
#include <math.h>

// ---------------- problem constants (fixed by setup_inputs) ----------------
#define NB   32      // batch
#define NQn  100     // num_queries
#define NN   3200    // NB*NQn
#define DM   256     // d_model
#define NH   8       // heads
#define HDd  32      // head dim
#define TT   3840    // total temporal length
// temporal shapes: 2048,1024,512,256  -> Tl = 2048>>l, start = 4096-(4096>>l)

typedef __attribute__((ext_vector_type(8))) short bf16x8;
typedef __attribute__((ext_vector_type(4))) float f32x4;

__device__ __forceinline__ float fast_tanh(float x) {
    float t = __expf(2.0f * x);
    return 1.0f - 2.0f * __builtin_amdgcn_rcpf(t + 1.0f);
}
__device__ __forceinline__ float fast_sigmoid(float x) {
    return __builtin_amdgcn_rcpf(1.0f + __expf(-x));
}
__device__ __forceinline__ unsigned short f2b(float f) {
    unsigned u = __float_as_uint(f);
    unsigned r = u + 0x7FFF + ((u >> 16) & 1);   // RNE
    return (unsigned short)(r >> 16);
}
__device__ __forceinline__ float b2f(unsigned short h) {
    return __uint_as_float((unsigned)h << 16);
}
// pack two f32 -> two bf16 (truncate) in ONE v_perm_b32
__device__ __forceinline__ unsigned pack2_trunc(float lo, float hi) {
    return __builtin_amdgcn_perm(__float_as_uint(hi), __float_as_uint(lo), 0x07060302u);
}

// ---------------- K0: weight prep -> bf16 fragment-major layouts ----------------
__global__ __launch_bounds__(256) void k0_prep(const float* __restrict__ Wih,
                                               const float* __restrict__ Whh,
                                               const float* __restrict__ Wctx,
                                               const float* __restrict__ Wv,
                                               const float* __restrict__ Woff,
                                               const float* __restrict__ Waw,
                                               const float* __restrict__ Whs,
                                               unsigned short* __restrict__ Wcatfrag,
                                               unsigned short* __restrict__ Wvfrag,
                                               unsigned short* __restrict__ Wfragb,
                                               unsigned short* __restrict__ Wk1frag) {
    int bid = blockIdx.x;
    int tid = threadIdx.x;
    if (bid < 256) {
        int cb = bid >> 2, q8 = bid & 3;
#pragma unroll
        for (int t2 = 0; t2 < 2; ++t2) {
            int idx = tid + t2 * 256;               // 0..511
            int s = q8 * 8 + (idx >> 6);            // k-step 0..31
            int lane = idx & 63;
            int col = cb * 16 + (lane & 15);
            int kb = s * 32 + (lane >> 4) * 8;
            float vv[8];
            if (kb < 768) {
#pragma unroll
                for (int j = 0; j < 8; ++j) vv[j] = Wih[col * 768 + kb + j];
            } else {
#pragma unroll
                for (int j = 0; j < 8; ++j) vv[j] = Whh[col * 256 + (kb - 768) + j];
            }
            uint4 w;
            w.x = (unsigned)f2b(vv[0]) | ((unsigned)f2b(vv[1]) << 16);
            w.y = (unsigned)f2b(vv[2]) | ((unsigned)f2b(vv[3]) << 16);
            w.z = (unsigned)f2b(vv[4]) | ((unsigned)f2b(vv[5]) << 16);
            w.w = (unsigned)f2b(vv[6]) | ((unsigned)f2b(vv[7]) << 16);
            *(uint4*)&Wcatfrag[(((cb * 32) + s) * 64 + lane) * 8] = w;
        }
    } else if (bid < 272) {
        int cb = bid - 256;
#pragma unroll
        for (int t2 = 0; t2 < 2; ++t2) {
            int idx = tid + t2 * 256;               // 0..511
            int s = idx >> 6;                       // 0..7
            int lane = idx & 63;
            int n = cb * 16 + (lane & 15);
            int kb = s * 32 + (lane >> 4) * 8;
            float vv[8];
#pragma unroll
            for (int j = 0; j < 8; ++j) vv[j] = Wv[(kb + j) * 256 + n];
            uint4 w;
            w.x = (unsigned)f2b(vv[0]) | ((unsigned)f2b(vv[1]) << 16);
            w.y = (unsigned)f2b(vv[2]) | ((unsigned)f2b(vv[3]) << 16);
            w.z = (unsigned)f2b(vv[4]) | ((unsigned)f2b(vv[5]) << 16);
            w.w = (unsigned)f2b(vv[6]) | ((unsigned)f2b(vv[7]) << 16);
            *(uint4*)&Wvfrag[(((cb * 8) + s) * 64 + lane) * 8] = w;
        }
    } else if (bid == 272) {
#pragma unroll
        for (int s4 = 0; s4 < 4; ++s4) {
            int slot = tid * 4 + s4;          // 0..1023
            int et = slot >> 6, lane = slot & 63;
            int e = et * 16 + (lane & 15);
            int kb = (lane >> 4) * 8;
            unsigned short o[8];
#pragma unroll
            for (int j = 0; j < 8; ++j) o[j] = f2b(Wctx[(kb + j) * 256 + e]);
            *(uint4*)&Wfragb[slot * 8] = *(uint4*)o;
        }
    } else {
        int cb = bid - 273;                    // 0..31
#pragma unroll
        for (int t4 = 0; t4 < 4; ++t4) {
            int idx = tid + t4 * 256;          // 0..1023 = 16 s x 64 lanes
            int s = idx >> 6, lane = idx & 63;
            int col = cb * 16 + (lane & 15);
            int kb = s * 32 + (lane >> 4) * 8;
            float vv[8];
            if (cb < 8) {
#pragma unroll
                for (int j = 0; j < 8; ++j) vv[j] = Woff[(kb + j) * 128 + col];
            } else if (cb < 16) {
#pragma unroll
                for (int j = 0; j < 8; ++j) vv[j] = Waw[(kb + j) * 128 + (col - 128)];
            } else if (kb < 256) {
#pragma unroll
                for (int j = 0; j < 8; ++j) vv[j] = Whs[(kb + j) * 256 + (col - 256)];
            } else {
#pragma unroll
                for (int j = 0; j < 8; ++j) vv[j] = 0.0f;
            }
            uint4 w;
            w.x = (unsigned)f2b(vv[0]) | ((unsigned)f2b(vv[1]) << 16);
            w.y = (unsigned)f2b(vv[2]) | ((unsigned)f2b(vv[3]) << 16);
            w.z = (unsigned)f2b(vv[4]) | ((unsigned)f2b(vv[5]) << 16);
            w.w = (unsigned)f2b(vv[6]) | ((unsigned)f2b(vv[7]) << 16);
            *(uint4*)&Wk1frag[(((cb * 16) + s) * 64 + lane) * 8] = w;
        }
    }
}

// ---------------- K1: off / aw(softmaxed) / hsb via MFMA ----------------
__global__ __launch_bounds__(256) void k1_proj(const float* __restrict__ h0,
                                               const float* __restrict__ query,
                                               const unsigned short* __restrict__ Wk1frag,
                                               const float* __restrict__ boff,
                                               const float* __restrict__ baw,
                                               const float* __restrict__ bhs,
                                               float* __restrict__ offb,
                                               float* __restrict__ awb,
                                               float* __restrict__ hsbb) {
    __shared__ __align__(16) unsigned short als[8192];   // 16 slots x 64 lanes x 8
    __shared__ float awl[16][132];
    int tid = threadIdx.x;
    int n0 = blockIdx.x * 16;
    int y  = blockIdx.y;

#pragma unroll
    for (int i = 0; i < 4; ++i) {
        int r  = (tid & 7) + 8 * (i & 1);         // 0..15
        int kg = (tid >> 3) + 32 * (i >> 1);      // 0..63
        const float* base = (i >> 1) ? query : h0;
        const float* p = base + (size_t)(n0 + r) * 256 + (kg & 31) * 8;
        float4 u = *(const float4*)p;
        float4 v = *(const float4*)(p + 4);
        int s = kg >> 2, q = kg & 3;
        uint4 w;
        w.x = (unsigned)f2b(u.x) | ((unsigned)f2b(u.y) << 16);
        w.y = (unsigned)f2b(u.z) | ((unsigned)f2b(u.w) << 16);
        w.z = (unsigned)f2b(v.x) | ((unsigned)f2b(v.y) << 16);
        w.w = (unsigned)f2b(v.z) | ((unsigned)f2b(v.w) << 16);
        *(uint4*)&als[((s * 64) + (r & 15) + 16 * q) * 8] = w;
    }
    __syncthreads();

    int w = tid >> 6, lane = tid & 63;
    int l16 = lane & 15, quad = lane >> 4;
    int smax = (y >= 2) ? 8 : 16;        // hsb K=256 (upper half zeros)

    f32x4 acc[2];
    f32x4 zero = {0.f, 0.f, 0.f, 0.f};
    acc[0] = zero; acc[1] = zero;

#pragma unroll 8
    for (int s = 0; s < smax; ++s) {
        bf16x8 a = *(bf16x8*)&als[(s * 64 + lane) * 8];
#pragma unroll
        for (int ct = 0; ct < 2; ++ct) {
            int cb = y * 8 + w * 2 + ct;
            bf16x8 bfr = *(const bf16x8*)&Wk1frag[(((cb * 16) + s) * 64 + lane) * 8];
            acc[ct] = __builtin_amdgcn_mfma_f32_16x16x32_bf16(a, bfr, acc[ct], 0, 0, 0);
        }
    }

    if (y == 0) {
#pragma unroll
        for (int ct = 0; ct < 2; ++ct) {
            int col = w * 32 + ct * 16 + l16;
            float bo = boff[col];
#pragma unroll
            for (int reg = 0; reg < 4; ++reg)
                offb[(size_t)(n0 + quad * 4 + reg) * 128 + col] = acc[ct][reg] + bo;
        }
    } else if (y == 1) {
#pragma unroll
        for (int ct = 0; ct < 2; ++ct) {
            int col = w * 32 + ct * 16 + l16;
            float ba = baw[col];
#pragma unroll
            for (int reg = 0; reg < 4; ++reg)
                awl[quad * 4 + reg][col] = acc[ct][reg] + ba;
        }
        __syncthreads();
        if (tid < 128) {
            int r = tid >> 3, h = tid & 7;
            float s[16];
            float mx = -1e30f;
#pragma unroll
            for (int i = 0; i < 16; ++i) {
                s[i] = awl[r][h * 16 + i];
                mx = fmaxf(mx, s[i]);
            }
            float sum = 0.f;
#pragma unroll
            for (int i = 0; i < 16; ++i) { s[i] = __expf(s[i] - mx); sum += s[i]; }
            float inv = 1.0f / sum;
#pragma unroll
            for (int i = 0; i < 16; ++i)
                awb[(size_t)(n0 + r) * 128 + h * 16 + i] = s[i] * inv;
        }
    } else {
#pragma unroll
        for (int ct = 0; ct < 2; ++ct) {
            int colh = (y - 2) * 128 + w * 32 + ct * 16 + l16;
            float bh = bhs[colh];
#pragma unroll
            for (int reg = 0; reg < 4; ++reg)
                hsbb[(size_t)(n0 + quad * 4 + reg) * 256 + colh] = acc[ct][reg] + bh;
        }
    }
}

// ---------------- K2a: streaming convert eh f32 -> bf16 ----------------
// 3840 blocks x 256 threads; 4 independent iterations of 16B-load/16B... (32B load,
// 16B store) per thread. Pure bandwidth.
__global__ __launch_bounds__(256) void k2a_cvt(const float* __restrict__ eh,
                                               unsigned short* __restrict__ ehb) {
    int tid = threadIdx.x;
    size_t base = (size_t)blockIdx.x * 8192;
#pragma unroll
    for (int it = 0; it < 4; ++it) {
        size_t off = base + (size_t)(it * 256 + tid) * 8;
        float4 u = *(const float4*)&eh[off];
        float4 v = *(const float4*)&eh[off + 4];
        uint4 w;
        w.x = pack2_trunc(u.x, u.y);
        w.y = pack2_trunc(u.z, u.w);
        w.z = pack2_trunc(v.x, v.y);
        w.w = pack2_trunc(v.z, v.w);
        *(uint4*)&ehb[off] = w;
    }
}

// ---------------- K2b: value = ehb @ W_value + b_value (bf16 A direct) ----------
// 1920 blocks; wave tile 16 rows x 256 cols. A-frag = ONE dwordx4/lane; 8 unrolled
// s-steps -> 8 A loads in flight. B frags L2-hot. Epilogue via padded LDS.
__global__ __launch_bounds__(256) void k2b_value(const unsigned short* __restrict__ ehb,
                                                 const unsigned short* __restrict__ Wvfrag,
                                                 const float* __restrict__ bv,
                                                 unsigned short* __restrict__ valueb) {
    __shared__ __align__(16) unsigned short lt[4][16 * 264];   // 33,792 B
    int tid = threadIdx.x;
    int w = tid >> 6, lane = tid & 63;
    int l16 = lane & 15, quad = lane >> 4;
    int m0 = blockIdx.x * 64 + w * 16;

    f32x4 acc[16];
    f32x4 zero = {0.f, 0.f, 0.f, 0.f};
#pragma unroll
    for (int nt = 0; nt < 16; ++nt) acc[nt] = zero;

#pragma unroll
    for (int s = 0; s < 8; ++s) {
        bf16x8 a = *(const bf16x8*)&ehb[(size_t)(m0 + l16) * 256 + s * 32 + quad * 8];
#pragma unroll
        for (int nt = 0; nt < 16; ++nt) {
            bf16x8 bfr = *(const bf16x8*)&Wvfrag[(((nt * 8) + s) * 64 + lane) * 8];
            acc[nt] = __builtin_amdgcn_mfma_f32_16x16x32_bf16(a, bfr, acc[nt], 0, 0, 0);
        }
    }

    unsigned short* myl = lt[w];
#pragma unroll
    for (int nt = 0; nt < 16; ++nt) {
        float bvv = bv[nt * 16 + l16];
#pragma unroll
        for (int reg = 0; reg < 4; ++reg)
            myl[(quad * 4 + reg) * 264 + nt * 16 + l16] = f2b(acc[nt][reg] + bvv);
    }
    __syncthreads();
#pragma unroll
    for (int i = 0; i < 8; ++i) {
        int idx = i * 64 + lane;        // 0..511
        int lr = idx >> 5, c = idx & 31;
        *(uint4*)&valueb[(size_t)(m0 + lr) * 256 + c * 8] = *(uint4*)&myl[lr * 264 + c * 8];
    }
}

// ---------------- K3: deformable sampling + MFMA additive attention ----------------
__global__ __launch_bounds__(256) void k3_attn(const float* __restrict__ rp,
                                               const float* __restrict__ offb,
                                               const float* __restrict__ awb,
                                               const float* __restrict__ hsbb,
                                               const unsigned short* __restrict__ valueb,
                                               const unsigned short* __restrict__ Wfragb,
                                               const float* __restrict__ bctx,
                                               const float* __restrict__ walpha,
                                               float* __restrict__ attnres) {
    __shared__ __align__(16) unsigned short featsb[128 * 40];  // bf16, row pad 40
    __shared__ float hb[256];       // bctx + hsb row
    __shared__ float wa[256];       // walpha
    __shared__ float scores[128];
    __shared__ float weight[8][16];

    int n = blockIdx.x;
    int b = n / NQn;
    int tid = threadIdx.x;

    {
        int pair = tid >> 1;
        int dh = (tid & 1) * 16;
        int h = pair >> 4;
        int lp = pair & 15;
        int l = lp >> 2;
        int Tli = 2048 >> l;
        int st = 4096 - (4096 >> l);
        float Tlf = (float)Tli;
        float invT = __uint_as_float((unsigned)(127 - (11 - l)) << 23);

        float r = rp[n * 4 + l];
        float off_v = offb[n * 128 + pair];
        float aw_v = awb[n * 128 + pair];
        float loc = r + off_v * invT;
        float x = loc * Tlf - 0.5f;
        float x0 = floorf(x);
        float w1 = x - x0;
        float w0 = 1.0f - w1;
        int i0 = (int)x0;
        int i1 = i0 + 1;
        float m0 = (i0 >= 0 && i0 < Tli) ? 1.0f : 0.0f;
        float m1 = (i1 >= 0 && i1 < Tli) ? 1.0f : 0.0f;
        int idx0 = min(max(i0, 0), Tli - 1);
        int idx1 = min(max(i1, 0), Tli - 1);
        float a0 = w0 * m0 * aw_v;
        float a1 = w1 * m1 * aw_v;
        const unsigned short* g0 = valueb + (size_t)(b * TT + st + idx0) * 256 + h * 32 + dh;
        const unsigned short* g1 = valueb + (size_t)(b * TT + st + idx1) * 256 + h * 32 + dh;
        union U8 { uint4 u; unsigned short s[8]; };
        U8 A0, A1, B0, B1;
        A0.u = *(const uint4*)g0;  A1.u = *(const uint4*)(g0 + 8);
        B0.u = *(const uint4*)g1;  B1.u = *(const uint4*)(g1 + 8);
        unsigned short o[16];
#pragma unroll
        for (int i = 0; i < 8; ++i) {
            o[i]     = f2b(b2f(A0.s[i]) * a0 + b2f(B0.s[i]) * a1);
            o[8 + i] = f2b(b2f(A1.s[i]) * a0 + b2f(B1.s[i]) * a1);
        }
        *(uint4*)&featsb[pair * 40 + dh]     = *(uint4*)&o[0];
        *(uint4*)&featsb[pair * 40 + dh + 8] = *(uint4*)&o[8];
    }
    hb[tid] = bctx[tid] + hsbb[n * 256 + tid];
    wa[tid] = walpha[tid];
    __syncthreads();

    {
        int w = tid >> 6, lane = tid & 63;
        int l16 = lane & 15, quad = lane >> 4;
        bf16x8 a0 = *(bf16x8*)&featsb[(w * 32 + l16) * 40 + quad * 8];
        bf16x8 a1 = *(bf16x8*)&featsb[(w * 32 + 16 + l16) * 40 + quad * 8];
        f32x4 zero = {0.f, 0.f, 0.f, 0.f};
        float sc0[4] = {0.f, 0.f, 0.f, 0.f};
        float sc1[4] = {0.f, 0.f, 0.f, 0.f};
#pragma unroll
        for (int et = 0; et < 16; ++et) {
            bf16x8 bfr = *(const bf16x8*)&Wfragb[(et * 64 + lane) * 8];
            float hbv = hb[et * 16 + l16];
            float wav = wa[et * 16 + l16];
            f32x4 z0 = __builtin_amdgcn_mfma_f32_16x16x32_bf16(a0, bfr, zero, 0, 0, 0);
            f32x4 z1 = __builtin_amdgcn_mfma_f32_16x16x32_bf16(a1, bfr, zero, 0, 0, 0);
#pragma unroll
            for (int reg = 0; reg < 4; ++reg) {
                sc0[reg] += wav * fast_tanh(z0[reg] + hbv);
                sc1[reg] += wav * fast_tanh(z1[reg] + hbv);
            }
        }
#pragma unroll
        for (int off = 1; off < 16; off <<= 1) {
#pragma unroll
            for (int reg = 0; reg < 4; ++reg) {
                sc0[reg] += __shfl_xor(sc0[reg], off);
                sc1[reg] += __shfl_xor(sc1[reg], off);
            }
        }
        if (l16 == 0) {
#pragma unroll
            for (int reg = 0; reg < 4; ++reg) {
                scores[w * 32 + quad * 4 + reg]      = sc0[reg];
                scores[w * 32 + 16 + quad * 4 + reg] = sc1[reg];
            }
        }
    }
    __syncthreads();

    if (tid < 8) {
        int h = tid;
        float s[16];
        float mx = -1e30f;
#pragma unroll
        for (int i = 0; i < 16; ++i) {
            s[i] = scores[h * 16 + i];
            mx = fmaxf(mx, s[i]);
        }
        float sum = 0.f;
#pragma unroll
        for (int i = 0; i < 16; ++i) { s[i] = __expf(s[i] - mx); sum += s[i]; }
        float inv = 1.0f / sum;
#pragma unroll
        for (int i = 0; i < 16; ++i) weight[h][i] = s[i] * inv;
    }
    __syncthreads();

    {
        int h = tid >> 5, d = tid & 31;
        float s = 0.f;
#pragma unroll
        for (int lp = 0; lp < 16; ++lp)
            s += weight[h][lp] * b2f(featsb[(h * 16 + lp) * 40 + d]);
        attnres[n * 256 + tid] = s;
    }
}

// ---------------- K4: LSTM gates GEMM (MFMA bf16) + fused gate nonlinearity ------
__global__ __launch_bounds__(256) void k4_lstm(const float* __restrict__ token,
                                               const float* __restrict__ attnres,
                                               const float* __restrict__ query,
                                               const float* __restrict__ h0,
                                               const unsigned short* __restrict__ Wcatfrag,
                                               const float* __restrict__ c0,
                                               float* __restrict__ out) {
    __shared__ __align__(16) unsigned short lds[16384];   // 32 slots x 64 lanes x 16 B
    int tid = threadIdx.x;
    int n0 = blockIdx.x * 16;
    int j0 = blockIdx.y * 64;

    const float* const srcs[4] = {token, attnres, query, h0};
#pragma unroll
    for (int i = 0; i < 8; ++i) {
        int c = i >> 1;                         // source segment (wave-uniform)
        int r = (tid & 7) + 8 * (i & 1);        // row 0..15
        int kgl = tid >> 3;                     // 8-col group 0..31 within segment
        const float* p = srcs[c] + (size_t)(n0 + r) * 256 + kgl * 8;
        float4 u = *(const float4*)p;
        float4 v = *(const float4*)(p + 4);
        int s = c * 8 + (kgl >> 2), q = kgl & 3;
        uint4 w;
        w.x = (unsigned)f2b(u.x) | ((unsigned)f2b(u.y) << 16);
        w.y = (unsigned)f2b(u.z) | ((unsigned)f2b(u.w) << 16);
        w.z = (unsigned)f2b(v.x) | ((unsigned)f2b(v.y) << 16);
        w.w = (unsigned)f2b(v.z) | ((unsigned)f2b(v.w) << 16);
        *(uint4*)&lds[((s * 64) + r + 16 * q) * 8] = w;
    }
    __syncthreads();

    int w = tid >> 6, lane = tid & 63;
    int l16 = lane & 15, quad = lane >> 4;
    int cbbase = (j0 >> 4) + w;

    f32x4 acc[4];
    f32x4 zero = {0.f, 0.f, 0.f, 0.f};
#pragma unroll
    for (int seg = 0; seg < 4; ++seg) acc[seg] = zero;

#pragma unroll 4
    for (int s = 0; s < 32; ++s) {
        bf16x8 a = *(bf16x8*)&lds[(s * 64 + lane) * 8];
#pragma unroll
        for (int seg = 0; seg < 4; ++seg) {
            bf16x8 bfr = *(const bf16x8*)&Wcatfrag[((((seg * 16 + cbbase) * 32) + s) * 64 + lane) * 8];
            acc[seg] = __builtin_amdgcn_mfma_f32_16x16x32_bf16(a, bfr, acc[seg], 0, 0, 0);
        }
    }

    int colg = j0 + w * 16 + l16;
#pragma unroll
    for (int reg = 0; reg < 4; ++reg) {
        int row = n0 + quad * 4 + reg;
        float gi = acc[0][reg];
        float gf = acc[1][reg];
        float gg = acc[2][reg];
        float go = acc[3][reg];
        float c0v = c0[row * 256 + colg];
        float cn = fast_sigmoid(gf) * c0v + fast_sigmoid(gi) * fast_tanh(gg);
        float hn = fast_sigmoid(go) * fast_tanh(cn);
        int o = row * 256 + colg;
        out[o] = hn;
        out[NN * 256 + o] = hn;
        out[2 * NN * 256 + o] = cn;
    }
}

// ---------------- launch ----------------
extern "C" void kernel_launch(void* const* d_in, const int* in_sizes, int n_in,
                              void* d_out, int out_size, void* d_ws, size_t ws_size,
                              hipStream_t stream) {
    (void)in_sizes; (void)n_in; (void)out_size; (void)ws_size;
    const float* token = (const float*)d_in[0];
    const float* h0    = (const float*)d_in[1];
    const float* c0    = (const float*)d_in[2];
    const float* query = (const float*)d_in[3];
    const float* rp    = (const float*)d_in[4];
    const float* eh    = (const float*)d_in[5];
    const float* Wv   = (const float*)d_in[8];
    const float* bv   = (const float*)d_in[9];
    const float* Woff = (const float*)d_in[10];
    const float* boff = (const float*)d_in[11];
    const float* Waw  = (const float*)d_in[12];
    const float* baw  = (const float*)d_in[13];
    const float* Wctx = (const float*)d_in[14];
    const float* bctx = (const float*)d_in[15];
    const float* Whs  = (const float*)d_in[16];
    const float* bhs  = (const float*)d_in[17];
    const float* Wal  = (const float*)d_in[18];
    const float* Wih  = (const float*)d_in[20];
    const float* Whh  = (const float*)d_in[21];
    float* out = (float*)d_out;

    char* ws = (char*)d_ws;
    unsigned short* valueb   = (unsigned short*)(ws);               // 62,914,560 B
    unsigned short* Wcatfrag = (unsigned short*)(ws + 62914560);    //  2,097,152 B
    unsigned short* Wvfrag   = (unsigned short*)(ws + 65011712);    //    131,072 B
    unsigned short* Wfragb   = (unsigned short*)(ws + 65142784);    //     16,384 B
    float* offb    = (float*)(ws + 65159168);                       //  1,638,400 B
    float* awb     = (float*)(ws + 66797568);                       //  1,638,400 B
    float* hsbb    = (float*)(ws + 68435968);                       //  3,276,800 B
    float* attnres = (float*)(ws + 71712768);                       //  3,276,800 B
    unsigned short* Wk1frag  = (unsigned short*)(ws + 74989568);    //  1,048,576 B
    unsigned short* ehb      = (unsigned short*)(ws + 76038144);    // 62,914,560 B

    k0_prep<<<305, 256, 0, stream>>>(Wih, Whh, Wctx, Wv, Woff, Waw, Whs,
                                     Wcatfrag, Wvfrag, Wfragb, Wk1frag);
    k1_proj<<<dim3(NN / 16, 4), 256, 0, stream>>>(h0, query, Wk1frag, boff, baw, bhs,
                                                  offb, awb, hsbb);
    k2a_cvt<<<3840, 256, 0, stream>>>(eh, ehb);
    k2b_value<<<(NB * TT) / 64, 256, 0, stream>>>(ehb, Wvfrag, bv, valueb);
    k3_attn<<<NN, 256, 0, stream>>>(rp, offb, awb, hsbb, valueb, Wfragb, bctx, Wal, attnres);
    k4_lstm<<<dim3(NN / 16, 4), 256, 0, stream>>>(token, attnres, query, h0, Wcatfrag, c0, out);
}

// Round 8
// 339.643 us; speedup vs baseline: 1.3713x; 1.3713x over previous
//
#include <hip/hip_runtime.h>
#include <math.h>

// ---------------- problem constants (fixed by setup_inputs) ----------------
#define NB   32      // batch
#define NQn  100     // num_queries
#define NN   3200    // NB*NQn
#define DM   256     // d_model
#define NH   8       // heads
#define HDd  32      // head dim
#define TT   3840    // total temporal length
// temporal shapes: 2048,1024,512,256  -> Tl = 2048>>l, start = 4096-(4096>>l)

typedef __attribute__((ext_vector_type(8))) short bf16x8;
typedef __attribute__((ext_vector_type(4))) float f32x4;

__device__ __forceinline__ float fast_tanh(float x) {
    float t = __expf(2.0f * x);
    return 1.0f - 2.0f * __builtin_amdgcn_rcpf(t + 1.0f);
}
__device__ __forceinline__ float fast_sigmoid(float x) {
    return __builtin_amdgcn_rcpf(1.0f + __expf(-x));
}
__device__ __forceinline__ unsigned short f2b(float f) {
    unsigned u = __float_as_uint(f);
    unsigned r = u + 0x7FFF + ((u >> 16) & 1);   // RNE
    return (unsigned short)(r >> 16);
}
__device__ __forceinline__ float b2f(unsigned short h) {
    return __uint_as_float((unsigned)h << 16);
}

// ---------------- K0: weight prep -> bf16 fragment-major layouts ----------------
__global__ __launch_bounds__(256) void k0_prep(const float* __restrict__ Wih,
                                               const float* __restrict__ Whh,
                                               const float* __restrict__ Wctx,
                                               const float* __restrict__ Wv,
                                               const float* __restrict__ Woff,
                                               const float* __restrict__ Waw,
                                               const float* __restrict__ Whs,
                                               unsigned short* __restrict__ Wcatfrag,
                                               unsigned short* __restrict__ Wvfrag,
                                               unsigned short* __restrict__ Wfragb,
                                               unsigned short* __restrict__ Wk1frag) {
    int bid = blockIdx.x;
    int tid = threadIdx.x;
    if (bid < 256) {
        int cb = bid >> 2, q8 = bid & 3;
#pragma unroll
        for (int t2 = 0; t2 < 2; ++t2) {
            int idx = tid + t2 * 256;               // 0..511
            int s = q8 * 8 + (idx >> 6);            // k-step 0..31
            int lane = idx & 63;
            int col = cb * 16 + (lane & 15);
            int kb = s * 32 + (lane >> 4) * 8;
            float vv[8];
            if (kb < 768) {
#pragma unroll
                for (int j = 0; j < 8; ++j) vv[j] = Wih[col * 768 + kb + j];
            } else {
#pragma unroll
                for (int j = 0; j < 8; ++j) vv[j] = Whh[col * 256 + (kb - 768) + j];
            }
            uint4 w;
            w.x = (unsigned)f2b(vv[0]) | ((unsigned)f2b(vv[1]) << 16);
            w.y = (unsigned)f2b(vv[2]) | ((unsigned)f2b(vv[3]) << 16);
            w.z = (unsigned)f2b(vv[4]) | ((unsigned)f2b(vv[5]) << 16);
            w.w = (unsigned)f2b(vv[6]) | ((unsigned)f2b(vv[7]) << 16);
            *(uint4*)&Wcatfrag[(((cb * 32) + s) * 64 + lane) * 8] = w;
        }
    } else if (bid < 272) {
        int cb = bid - 256;
#pragma unroll
        for (int t2 = 0; t2 < 2; ++t2) {
            int idx = tid + t2 * 256;               // 0..511
            int s = idx >> 6;                       // 0..7
            int lane = idx & 63;
            int n = cb * 16 + (lane & 15);
            int kb = s * 32 + (lane >> 4) * 8;
            float vv[8];
#pragma unroll
            for (int j = 0; j < 8; ++j) vv[j] = Wv[(kb + j) * 256 + n];
            uint4 w;
            w.x = (unsigned)f2b(vv[0]) | ((unsigned)f2b(vv[1]) << 16);
            w.y = (unsigned)f2b(vv[2]) | ((unsigned)f2b(vv[3]) << 16);
            w.z = (unsigned)f2b(vv[4]) | ((unsigned)f2b(vv[5]) << 16);
            w.w = (unsigned)f2b(vv[6]) | ((unsigned)f2b(vv[7]) << 16);
            *(uint4*)&Wvfrag[(((cb * 8) + s) * 64 + lane) * 8] = w;
        }
    } else if (bid == 272) {
#pragma unroll
        for (int s4 = 0; s4 < 4; ++s4) {
            int slot = tid * 4 + s4;          // 0..1023
            int et = slot >> 6, lane = slot & 63;
            int e = et * 16 + (lane & 15);
            int kb = (lane >> 4) * 8;
            unsigned short o[8];
#pragma unroll
            for (int j = 0; j < 8; ++j) o[j] = f2b(Wctx[(kb + j) * 256 + e]);
            *(uint4*)&Wfragb[slot * 8] = *(uint4*)o;
        }
    } else {
        int cb = bid - 273;                    // 0..31
#pragma unroll
        for (int t4 = 0; t4 < 4; ++t4) {
            int idx = tid + t4 * 256;          // 0..1023 = 16 s x 64 lanes
            int s = idx >> 6, lane = idx & 63;
            int col = cb * 16 + (lane & 15);
            int kb = s * 32 + (lane >> 4) * 8;
            float vv[8];
            if (cb < 8) {
#pragma unroll
                for (int j = 0; j < 8; ++j) vv[j] = Woff[(kb + j) * 128 + col];
            } else if (cb < 16) {
#pragma unroll
                for (int j = 0; j < 8; ++j) vv[j] = Waw[(kb + j) * 128 + (col - 128)];
            } else if (kb < 256) {
#pragma unroll
                for (int j = 0; j < 8; ++j) vv[j] = Whs[(kb + j) * 256 + (col - 256)];
            } else {
#pragma unroll
                for (int j = 0; j < 8; ++j) vv[j] = 0.0f;
            }
            uint4 w;
            w.x = (unsigned)f2b(vv[0]) | ((unsigned)f2b(vv[1]) << 16);
            w.y = (unsigned)f2b(vv[2]) | ((unsigned)f2b(vv[3]) << 16);
            w.z = (unsigned)f2b(vv[4]) | ((unsigned)f2b(vv[5]) << 16);
            w.w = (unsigned)f2b(vv[6]) | ((unsigned)f2b(vv[7]) << 16);
            *(uint4*)&Wk1frag[(((cb * 16) + s) * 64 + lane) * 8] = w;
        }
    }
}

// ---------------- K1: off / aw(softmaxed) / hsb via MFMA ----------------
__global__ __launch_bounds__(256) void k1_proj(const float* __restrict__ h0,
                                               const float* __restrict__ query,
                                               const unsigned short* __restrict__ Wk1frag,
                                               const float* __restrict__ boff,
                                               const float* __restrict__ baw,
                                               const float* __restrict__ bhs,
                                               float* __restrict__ offb,
                                               float* __restrict__ awb,
                                               float* __restrict__ hsbb) {
    __shared__ __align__(16) unsigned short als[8192];   // 16 slots x 64 lanes x 8
    __shared__ float awl[16][132];
    int tid = threadIdx.x;
    int n0 = blockIdx.x * 16;
    int y  = blockIdx.y;

#pragma unroll
    for (int i = 0; i < 4; ++i) {
        int r  = (tid & 7) + 8 * (i & 1);         // 0..15
        int kg = (tid >> 3) + 32 * (i >> 1);      // 0..63
        const float* base = (i >> 1) ? query : h0;
        const float* p = base + (size_t)(n0 + r) * 256 + (kg & 31) * 8;
        float4 u = *(const float4*)p;
        float4 v = *(const float4*)(p + 4);
        int s = kg >> 2, q = kg & 3;
        uint4 w;
        w.x = (unsigned)f2b(u.x) | ((unsigned)f2b(u.y) << 16);
        w.y = (unsigned)f2b(u.z) | ((unsigned)f2b(u.w) << 16);
        w.z = (unsigned)f2b(v.x) | ((unsigned)f2b(v.y) << 16);
        w.w = (unsigned)f2b(v.z) | ((unsigned)f2b(v.w) << 16);
        *(uint4*)&als[((s * 64) + (r & 15) + 16 * q) * 8] = w;
    }
    __syncthreads();

    int w = tid >> 6, lane = tid & 63;
    int l16 = lane & 15, quad = lane >> 4;
    int smax = (y >= 2) ? 8 : 16;        // hsb K=256 (upper half zeros)

    f32x4 acc[2];
    f32x4 zero = {0.f, 0.f, 0.f, 0.f};
    acc[0] = zero; acc[1] = zero;

#pragma unroll 8
    for (int s = 0; s < smax; ++s) {
        bf16x8 a = *(bf16x8*)&als[(s * 64 + lane) * 8];
#pragma unroll
        for (int ct = 0; ct < 2; ++ct) {
            int cb = y * 8 + w * 2 + ct;
            bf16x8 bfr = *(const bf16x8*)&Wk1frag[(((cb * 16) + s) * 64 + lane) * 8];
            acc[ct] = __builtin_amdgcn_mfma_f32_16x16x32_bf16(a, bfr, acc[ct], 0, 0, 0);
        }
    }

    if (y == 0) {
#pragma unroll
        for (int ct = 0; ct < 2; ++ct) {
            int col = w * 32 + ct * 16 + l16;
            float bo = boff[col];
#pragma unroll
            for (int reg = 0; reg < 4; ++reg)
                offb[(size_t)(n0 + quad * 4 + reg) * 128 + col] = acc[ct][reg] + bo;
        }
    } else if (y == 1) {
#pragma unroll
        for (int ct = 0; ct < 2; ++ct) {
            int col = w * 32 + ct * 16 + l16;
            float ba = baw[col];
#pragma unroll
            for (int reg = 0; reg < 4; ++reg)
                awl[quad * 4 + reg][col] = acc[ct][reg] + ba;
        }
        __syncthreads();
        if (tid < 128) {
            int r = tid >> 3, h = tid & 7;
            float s[16];
            float mx = -1e30f;
#pragma unroll
            for (int i = 0; i < 16; ++i) {
                s[i] = awl[r][h * 16 + i];
                mx = fmaxf(mx, s[i]);
            }
            float sum = 0.f;
#pragma unroll
            for (int i = 0; i < 16; ++i) { s[i] = __expf(s[i] - mx); sum += s[i]; }
            float inv = 1.0f / sum;
#pragma unroll
            for (int i = 0; i < 16; ++i)
                awb[(size_t)(n0 + r) * 128 + h * 16 + i] = s[i] * inv;
        }
    } else {
#pragma unroll
        for (int ct = 0; ct < 2; ++ct) {
            int colh = (y - 2) * 128 + w * 32 + ct * 16 + l16;
            float bh = bhs[colh];
#pragma unroll
            for (int reg = 0; reg < 4; ++reg)
                hsbb[(size_t)(n0 + quad * 4 + reg) * 256 + colh] = acc[ct][reg] + bh;
        }
    }
}

// ---------------- K2: value = EH @ W_value + b_value (high-TLP small tile) ------
// Block = 32 rows x 256 cols, grid 3840 (15 blocks/CU demand). LDS 16.9 KB.
// Staging: 8 independent dwordx4 loads/thread. Wave tile 32x64 (acc 32 VGPR).
// Epilogue: 264-stride padded transpose (measured conflict-free in R7).
__global__ __launch_bounds__(256) void k2_value(const float* __restrict__ eh,
                                                const unsigned short* __restrict__ Wvfrag,
                                                const float* __restrict__ bv,
                                                unsigned short* __restrict__ valueb) {
    __shared__ __align__(16) unsigned short lds[32 * 264];   // 16,896 B
    int tid = threadIdx.x;
    int m0 = blockIdx.x * 32;

    // stage 32x256 f32 -> A-frag bf16: slot (s,mt) s=0..7, mt=0..1
#pragma unroll
    for (int i = 0; i < 4; ++i) {
        int r = (tid & 7) + 8 * i;        // 0..31
        int kg = tid >> 3;                // 0..31
        const float* p = eh + (size_t)(m0 + r) * 256 + kg * 8;
        float4 u = *(const float4*)p;
        float4 v = *(const float4*)(p + 4);
        int s = kg >> 2, bq = kg & 3;
        int lane16 = (r & 15) + 16 * bq;
        int mt = r >> 4;
        uint4 w;
        w.x = (unsigned)f2b(u.x) | ((unsigned)f2b(u.y) << 16);
        w.y = (unsigned)f2b(u.z) | ((unsigned)f2b(u.w) << 16);
        w.z = (unsigned)f2b(v.x) | ((unsigned)f2b(v.y) << 16);
        w.w = (unsigned)f2b(v.z) | ((unsigned)f2b(v.w) << 16);
        *(uint4*)&lds[(((s * 2 + mt) * 64) + lane16) * 8] = w;
    }
    __syncthreads();

    int w = tid >> 6, lane = tid & 63;
    int l16 = lane & 15, quad = lane >> 4;

    f32x4 acc[2][4];
    f32x4 zero = {0.f, 0.f, 0.f, 0.f};
#pragma unroll
    for (int mt = 0; mt < 2; ++mt)
#pragma unroll
        for (int nt = 0; nt < 4; ++nt) acc[mt][nt] = zero;

#pragma unroll
    for (int s = 0; s < 8; ++s) {
        bf16x8 a0 = *(bf16x8*)&lds[(((s * 2 + 0) * 64) + lane) * 8];
        bf16x8 a1 = *(bf16x8*)&lds[(((s * 2 + 1) * 64) + lane) * 8];
#pragma unroll
        for (int nt = 0; nt < 4; ++nt) {
            int cb = w * 4 + nt;
            bf16x8 bfr = *(const bf16x8*)&Wvfrag[(((cb * 8) + s) * 64 + lane) * 8];
            acc[0][nt] = __builtin_amdgcn_mfma_f32_16x16x32_bf16(a0, bfr, acc[0][nt], 0, 0, 0);
            acc[1][nt] = __builtin_amdgcn_mfma_f32_16x16x32_bf16(a1, bfr, acc[1][nt], 0, 0, 0);
        }
    }
    __syncthreads();   // all A-frag reads done before epilogue overwrites lds

    // epilogue: +bias, ->bf16, padded transpose
#pragma unroll
    for (int nt = 0; nt < 4; ++nt) {
        int col = w * 64 + nt * 16 + l16;
        float bvv = bv[col];
#pragma unroll
        for (int mt = 0; mt < 2; ++mt) {
#pragma unroll
            for (int reg = 0; reg < 4; ++reg)
                lds[(mt * 16 + quad * 4 + reg) * 264 + col] = f2b(acc[mt][nt][reg] + bvv);
        }
    }
    __syncthreads();
#pragma unroll
    for (int i = 0; i < 2; ++i) {
        int idx = i * 256 + tid;       // 0..511 = 32 rows x 16 uint4... (32x32)
        int lr = idx >> 5, c = idx & 31;
        *(uint4*)&valueb[(size_t)(m0 + lr) * 256 + c * 8] = *(uint4*)&lds[lr * 264 + c * 8];
    }
}

// ---------------- K3: deformable sampling + MFMA additive attention ----------------
__global__ __launch_bounds__(256) void k3_attn(const float* __restrict__ rp,
                                               const float* __restrict__ offb,
                                               const float* __restrict__ awb,
                                               const float* __restrict__ hsbb,
                                               const unsigned short* __restrict__ valueb,
                                               const unsigned short* __restrict__ Wfragb,
                                               const float* __restrict__ bctx,
                                               const float* __restrict__ walpha,
                                               float* __restrict__ attnres) {
    __shared__ __align__(16) unsigned short featsb[128 * 40];  // bf16, row pad 40
    __shared__ float hb[256];       // bctx + hsb row
    __shared__ float wa[256];       // walpha
    __shared__ float scores[128];
    __shared__ float weight[8][16];

    int n = blockIdx.x;
    int b = n / NQn;
    int tid = threadIdx.x;

    {
        int pair = tid >> 1;
        int dh = (tid & 1) * 16;
        int h = pair >> 4;
        int lp = pair & 15;
        int l = lp >> 2;
        int Tli = 2048 >> l;
        int st = 4096 - (4096 >> l);
        float Tlf = (float)Tli;
        float invT = __uint_as_float((unsigned)(127 - (11 - l)) << 23);

        float r = rp[n * 4 + l];
        float off_v = offb[n * 128 + pair];
        float aw_v = awb[n * 128 + pair];
        float loc = r + off_v * invT;
        float x = loc * Tlf - 0.5f;
        float x0 = floorf(x);
        float w1 = x - x0;
        float w0 = 1.0f - w1;
        int i0 = (int)x0;
        int i1 = i0 + 1;
        float m0 = (i0 >= 0 && i0 < Tli) ? 1.0f : 0.0f;
        float m1 = (i1 >= 0 && i1 < Tli) ? 1.0f : 0.0f;
        int idx0 = min(max(i0, 0), Tli - 1);
        int idx1 = min(max(i1, 0), Tli - 1);
        float a0 = w0 * m0 * aw_v;
        float a1 = w1 * m1 * aw_v;
        const unsigned short* g0 = valueb + (size_t)(b * TT + st + idx0) * 256 + h * 32 + dh;
        const unsigned short* g1 = valueb + (size_t)(b * TT + st + idx1) * 256 + h * 32 + dh;
        union U8 { uint4 u; unsigned short s[8]; };
        U8 A0, A1, B0, B1;
        A0.u = *(const uint4*)g0;  A1.u = *(const uint4*)(g0 + 8);
        B0.u = *(const uint4*)g1;  B1.u = *(const uint4*)(g1 + 8);
        unsigned short o[16];
#pragma unroll
        for (int i = 0; i < 8; ++i) {
            o[i]     = f2b(b2f(A0.s[i]) * a0 + b2f(B0.s[i]) * a1);
            o[8 + i] = f2b(b2f(A1.s[i]) * a0 + b2f(B1.s[i]) * a1);
        }
        *(uint4*)&featsb[pair * 40 + dh]     = *(uint4*)&o[0];
        *(uint4*)&featsb[pair * 40 + dh + 8] = *(uint4*)&o[8];
    }
    hb[tid] = bctx[tid] + hsbb[n * 256 + tid];
    wa[tid] = walpha[tid];
    __syncthreads();

    {
        int w = tid >> 6, lane = tid & 63;
        int l16 = lane & 15, quad = lane >> 4;
        bf16x8 a0 = *(bf16x8*)&featsb[(w * 32 + l16) * 40 + quad * 8];
        bf16x8 a1 = *(bf16x8*)&featsb[(w * 32 + 16 + l16) * 40 + quad * 8];
        f32x4 zero = {0.f, 0.f, 0.f, 0.f};
        float sc0[4] = {0.f, 0.f, 0.f, 0.f};
        float sc1[4] = {0.f, 0.f, 0.f, 0.f};
#pragma unroll
        for (int et = 0; et < 16; ++et) {
            bf16x8 bfr = *(const bf16x8*)&Wfragb[(et * 64 + lane) * 8];
            float hbv = hb[et * 16 + l16];
            float wav = wa[et * 16 + l16];
            f32x4 z0 = __builtin_amdgcn_mfma_f32_16x16x32_bf16(a0, bfr, zero, 0, 0, 0);
            f32x4 z1 = __builtin_amdgcn_mfma_f32_16x16x32_bf16(a1, bfr, zero, 0, 0, 0);
#pragma unroll
            for (int reg = 0; reg < 4; ++reg) {
                sc0[reg] += wav * fast_tanh(z0[reg] + hbv);
                sc1[reg] += wav * fast_tanh(z1[reg] + hbv);
            }
        }
#pragma unroll
        for (int off = 1; off < 16; off <<= 1) {
#pragma unroll
            for (int reg = 0; reg < 4; ++reg) {
                sc0[reg] += __shfl_xor(sc0[reg], off);
                sc1[reg] += __shfl_xor(sc1[reg], off);
            }
        }
        if (l16 == 0) {
#pragma unroll
            for (int reg = 0; reg < 4; ++reg) {
                scores[w * 32 + quad * 4 + reg]      = sc0[reg];
                scores[w * 32 + 16 + quad * 4 + reg] = sc1[reg];
            }
        }
    }
    __syncthreads();

    if (tid < 8) {
        int h = tid;
        float s[16];
        float mx = -1e30f;
#pragma unroll
        for (int i = 0; i < 16; ++i) {
            s[i] = scores[h * 16 + i];
            mx = fmaxf(mx, s[i]);
        }
        float sum = 0.f;
#pragma unroll
        for (int i = 0; i < 16; ++i) { s[i] = __expf(s[i] - mx); sum += s[i]; }
        float inv = 1.0f / sum;
#pragma unroll
        for (int i = 0; i < 16; ++i) weight[h][i] = s[i] * inv;
    }
    __syncthreads();

    {
        int h = tid >> 5, d = tid & 31;
        float s = 0.f;
#pragma unroll
        for (int lp = 0; lp < 16; ++lp)
            s += weight[h][lp] * b2f(featsb[(h * 16 + lp) * 40 + d]);
        attnres[n * 256 + tid] = s;
    }
}

// ---------------- K4: LSTM gates GEMM (MFMA bf16) + fused gate nonlinearity ------
__global__ __launch_bounds__(256) void k4_lstm(const float* __restrict__ token,
                                               const float* __restrict__ attnres,
                                               const float* __restrict__ query,
                                               const float* __restrict__ h0,
                                               const unsigned short* __restrict__ Wcatfrag,
                                               const float* __restrict__ c0,
                                               float* __restrict__ out) {
    __shared__ __align__(16) unsigned short lds[16384];   // 32 slots x 64 lanes x 16 B
    int tid = threadIdx.x;
    int n0 = blockIdx.x * 16;
    int j0 = blockIdx.y * 64;

    const float* const srcs[4] = {token, attnres, query, h0};
#pragma unroll
    for (int i = 0; i < 8; ++i) {
        int c = i >> 1;                         // source segment (wave-uniform)
        int r = (tid & 7) + 8 * (i & 1);        // row 0..15
        int kgl = tid >> 3;                     // 8-col group 0..31 within segment
        const float* p = srcs[c] + (size_t)(n0 + r) * 256 + kgl * 8;
        float4 u = *(const float4*)p;
        float4 v = *(const float4*)(p + 4);
        int s = c * 8 + (kgl >> 2), q = kgl & 3;
        uint4 w;
        w.x = (unsigned)f2b(u.x) | ((unsigned)f2b(u.y) << 16);
        w.y = (unsigned)f2b(u.z) | ((unsigned)f2b(u.w) << 16);
        w.z = (unsigned)f2b(v.x) | ((unsigned)f2b(v.y) << 16);
        w.w = (unsigned)f2b(v.z) | ((unsigned)f2b(v.w) << 16);
        *(uint4*)&lds[((s * 64) + r + 16 * q) * 8] = w;
    }
    __syncthreads();

    int w = tid >> 6, lane = tid & 63;
    int l16 = lane & 15, quad = lane >> 4;
    int cbbase = (j0 >> 4) + w;

    f32x4 acc[4];
    f32x4 zero = {0.f, 0.f, 0.f, 0.f};
#pragma unroll
    for (int seg = 0; seg < 4; ++seg) acc[seg] = zero;

#pragma unroll 4
    for (int s = 0; s < 32; ++s) {
        bf16x8 a = *(bf16x8*)&lds[(s * 64 + lane) * 8];
#pragma unroll
        for (int seg = 0; seg < 4; ++seg) {
            bf16x8 bfr = *(const bf16x8*)&Wcatfrag[((((seg * 16 + cbbase) * 32) + s) * 64 + lane) * 8];
            acc[seg] = __builtin_amdgcn_mfma_f32_16x16x32_bf16(a, bfr, acc[seg], 0, 0, 0);
        }
    }

    int colg = j0 + w * 16 + l16;
#pragma unroll
    for (int reg = 0; reg < 4; ++reg) {
        int row = n0 + quad * 4 + reg;
        float gi = acc[0][reg];
        float gf = acc[1][reg];
        float gg = acc[2][reg];
        float go = acc[3][reg];
        float c0v = c0[row * 256 + colg];
        float cn = fast_sigmoid(gf) * c0v + fast_sigmoid(gi) * fast_tanh(gg);
        float hn = fast_sigmoid(go) * fast_tanh(cn);
        int o = row * 256 + colg;
        out[o] = hn;
        out[NN * 256 + o] = hn;
        out[2 * NN * 256 + o] = cn;
    }
}

// ---------------- launch ----------------
extern "C" void kernel_launch(void* const* d_in, const int* in_sizes, int n_in,
                              void* d_out, int out_size, void* d_ws, size_t ws_size,
                              hipStream_t stream) {
    (void)in_sizes; (void)n_in; (void)out_size; (void)ws_size;
    const float* token = (const float*)d_in[0];
    const float* h0    = (const float*)d_in[1];
    const float* c0    = (const float*)d_in[2];
    const float* query = (const float*)d_in[3];
    const float* rp    = (const float*)d_in[4];
    const float* eh    = (const float*)d_in[5];
    const float* Wv   = (const float*)d_in[8];
    const float* bv   = (const float*)d_in[9];
    const float* Woff = (const float*)d_in[10];
    const float* boff = (const float*)d_in[11];
    const float* Waw  = (const float*)d_in[12];
    const float* baw  = (const float*)d_in[13];
    const float* Wctx = (const float*)d_in[14];
    const float* bctx = (const float*)d_in[15];
    const float* Whs  = (const float*)d_in[16];
    const float* bhs  = (const float*)d_in[17];
    const float* Wal  = (const float*)d_in[18];
    const float* Wih  = (const float*)d_in[20];
    const float* Whh  = (const float*)d_in[21];
    float* out = (float*)d_out;

    char* ws = (char*)d_ws;
    unsigned short* valueb   = (unsigned short*)(ws);               // 62,914,560 B
    unsigned short* Wcatfrag = (unsigned short*)(ws + 62914560);    //  2,097,152 B
    unsigned short* Wvfrag   = (unsigned short*)(ws + 65011712);    //    131,072 B
    unsigned short* Wfragb   = (unsigned short*)(ws + 65142784);    //     16,384 B
    float* offb    = (float*)(ws + 65159168);                       //  1,638,400 B
    float* awb     = (float*)(ws + 66797568);                       //  1,638,400 B
    float* hsbb    = (float*)(ws + 68435968);                       //  3,276,800 B
    float* attnres = (float*)(ws + 71712768);                       //  3,276,800 B
    unsigned short* Wk1frag  = (unsigned short*)(ws + 74989568);    //  1,048,576 B

    k0_prep<<<305, 256, 0, stream>>>(Wih, Whh, Wctx, Wv, Woff, Waw, Whs,
                                     Wcatfrag, Wvfrag, Wfragb, Wk1frag);
    k1_proj<<<dim3(NN / 16, 4), 256, 0, stream>>>(h0, query, Wk1frag, boff, baw, bhs,
                                                  offb, awb, hsbb);
    k2_value<<<(NB * TT) / 32, 256, 0, stream>>>(eh, Wvfrag, bv, valueb);
    k3_attn<<<NN, 256, 0, stream>>>(rp, offb, awb, hsbb, valueb, Wfragb, bctx, Wal, attnres);
    k4_lstm<<<dim3(NN / 16, 4), 256, 0, stream>>>(token, attnres, query, h0, Wcatfrag, c0, out);
}